// Round 5
// baseline (547.940 us; speedup 1.0000x reference)
//
#include <hip/hip_runtime.h>

#define B_ 4
#define S_ 2048
#define D_ 1024
#define M_ (B_*S_)           // 8192
#define K2_ 2048
#define N2_ 2048
#define NTOT (B_*S_*D_)      // 8388608
#define DD (D_*D_)           // 1048576
#define NPAIR 36             // upper-triangle 128-tiles of 8x8
#define GBYTES (B_*NPAIR*16384*4)   // 9437184

typedef __attribute__((ext_vector_type(4))) float f32x4;
typedef __attribute__((ext_vector_type(8))) short short8;
typedef __attribute__((ext_vector_type(4))) unsigned short u16x4;
typedef __attribute__((ext_vector_type(8))) unsigned short u16x8;

static __device__ __forceinline__ unsigned short f2bf(float f) {
    union { float f; unsigned int u; } v; v.f = f;
    unsigned int u = v.u;
    unsigned int r = (u + 0x7fffu + ((u >> 16) & 1u)) >> 16;
    return (unsigned short)r;
}
static __device__ __forceinline__ float bf2f(unsigned short h) {
    union { unsigned int u; float f; } v; v.u = ((unsigned int)h) << 16;
    return v.f;
}

// scal layout (fp32 slots): [0..1] sumsq[l], [2..9] diff2[l*4+b],
// [10..17] prev2[l*4+b], [18..25] diag-max bits, [26..33] diag-min bits,
// [64..2111] dampv[2][1024]

// ---------------------------------------------------------------------------
// gemm_main2: paired-tile mixing GEMM (905 TF verified r3). Block (nt, mt)
// computes real+imag column tiles against one A tile. Emits bd2, raw |bd|
// transposed into magT[b][d][s], and sum(bd^2).
// ---------------------------------------------------------------------------
__global__ __launch_bounds__(256, 2) void gemm_main2(const unsigned short* __restrict__ A2,
                                                     const unsigned short* __restrict__ B2T,
                                                     unsigned short* __restrict__ bd2,
                                                     unsigned short* __restrict__ magT,
                                                     float* __restrict__ scal, int l)
{
    __shared__ unsigned short smem[3 * 128 * 64];   // 48 KB: As | Bsr | Bsi
    __shared__ float red[4];
    unsigned short* As  = smem;
    unsigned short* Bsr = smem + 8192;
    unsigned short* Bsi = smem + 16384;

    f32x4 accr[4][4], acci[4][4];
#pragma unroll
    for (int i = 0; i < 4; ++i)
#pragma unroll
        for (int j = 0; j < 4; ++j) { accr[i][j] = (f32x4)0.0f; acci[i][j] = (f32x4)0.0f; }

    const int nt = blockIdx.x, mt = blockIdx.y;
    const int tid = threadIdx.x, wave = tid >> 6, lane = tid & 63;
    const int q = lane >> 4, lm = lane & 15;
    const int wm = (wave >> 1) * 64, wn = (wave & 1) * 64;
    const int crow = lane >> 3;
    const int gcol = ((lane & 7) ^ crow) * 8;

    const unsigned short* Ag  = A2  + (long)mt * 128 * K2_;
    const unsigned short* Bgr = B2T + (long)(nt * 128) * K2_;
    const unsigned short* Bgi = B2T + (long)(nt * 128 + 1024) * K2_;

    for (int kt = 0; kt < K2_ / 64; ++kt) {
        const long k0 = (long)kt * 64;
        __syncthreads();
#pragma unroll
        for (int i2 = 0; i2 < 4; ++i2) {
            int c   = i2 * 4 + wave;
            int row = c * 8 + crow;
            long go = (long)row * K2_ + k0 + gcol;
            __builtin_amdgcn_global_load_lds((const __attribute__((address_space(1))) void*)(Ag + go),
                                             (__attribute__((address_space(3))) void*)(As + c * 512), 16, 0, 0);
            __builtin_amdgcn_global_load_lds((const __attribute__((address_space(1))) void*)(Bgr + go),
                                             (__attribute__((address_space(3))) void*)(Bsr + c * 512), 16, 0, 0);
            __builtin_amdgcn_global_load_lds((const __attribute__((address_space(1))) void*)(Bgi + go),
                                             (__attribute__((address_space(3))) void*)(Bsi + c * 512), 16, 0, 0);
        }
        __syncthreads();
#pragma unroll
        for (int kk = 0; kk < 64; kk += 32) {
            short8 a[4], br[4], bi[4];
#pragma unroll
            for (int t = 0; t < 4; ++t) {
                int arow  = wm + t * 16 + lm;
                int aslot = ((kk >> 3) + q) ^ (arow & 7);
                a[t] = *(const short8*)(As + arow * 64 + aslot * 8);
                int brow  = wn + t * 16 + lm;
                int bslot = ((kk >> 3) + q) ^ (brow & 7);
                br[t] = *(const short8*)(Bsr + brow * 64 + bslot * 8);
                bi[t] = *(const short8*)(Bsi + brow * 64 + bslot * 8);
            }
#pragma unroll
            for (int um = 0; um < 4; ++um)
#pragma unroll
                for (int un = 0; un < 4; ++un) {
                    accr[um][un] = __builtin_amdgcn_mfma_f32_16x16x32_bf16(a[um], br[un], accr[um][un], 0, 0, 0);
                    acci[um][un] = __builtin_amdgcn_mfma_f32_16x16x32_bf16(a[um], bi[un], acci[um][un], 0, 0, 0);
                }
        }
    }

    __syncthreads();
    unsigned short* magLds = smem;       // [128 d][136 stride] bf16
    float ss = 0.f;
#pragma unroll
    for (int um = 0; um < 4; ++um) {
#pragma unroll
        for (int un = 0; un < 4; ++un) {
            int colb = wn + un * 16 + lm;
            int coln = nt * 128 + colb;
            u16x4 magv;
#pragma unroll
            for (int i = 0; i < 4; ++i) {
                long rowm = (long)mt * 128 + wm + um * 16 + q * 4 + i;
                float vr = accr[um][un][i];
                float vi = acci[um][un][i];
                bd2[rowm * N2_ + coln]        = f2bf(vr);
                bd2[rowm * N2_ + 1024 + coln] = f2bf(vi);
                float s2 = vr * vr + vi * vi;
                ss += s2;
                magv[i] = f2bf(sqrtf(s2));
            }
            *(u16x4*)(magLds + colb * 136 + wm + um * 16 + q * 4) = magv;
        }
    }
    for (int off = 32; off > 0; off >>= 1) ss += __shfl_down(ss, off);
    if (lane == 0) red[wave] = ss;
    __syncthreads();
    if (tid == 0) atomicAdd(scal + l, red[0] + red[1] + red[2] + red[3]);

    const int b   = mt >> 4;
    const long s0 = (long)(mt & 15) * 128;
#pragma unroll
    for (int it = 0; it < 8; ++it) {
        int sid = it * 256 + tid;
        int row = sid >> 4, seg = sid & 15;
        unsigned short* dst = magT + (long)b * D_ * S_ + (long)(nt * 128 + row) * S_ + s0 + seg * 8;
        *(u16x8*)dst = *(const u16x8*)(magLds + row * 136 + seg * 8);
    }
}

// 128x128 MFMA core (XOR-swizzled LDS), generic strides/kiters
__device__ __forceinline__ void mfma_gemm_128(const unsigned short* __restrict__ Ag, long astride,
                                              const unsigned short* __restrict__ Bg, long bstride,
                                              int kiters,
                                              unsigned short* As, unsigned short* Bs,
                                              f32x4 acc[4][4])
{
    const int tid  = threadIdx.x;
    const int wave = tid >> 6, lane = tid & 63;
    const int q    = lane >> 4, lm = lane & 15;
    const int wm   = (wave >> 1) * 64, wn = (wave & 1) * 64;
    const int crow = lane >> 3;
    const int gcol = ((lane & 7) ^ crow) * 8;

    for (int kt = 0; kt < kiters; ++kt) {
        const long k0 = (long)kt * 64;
        __syncthreads();
#pragma unroll
        for (int i2 = 0; i2 < 4; ++i2) {
            int c   = i2 * 4 + wave;
            int row = c * 8 + crow;
            const unsigned short* ga = Ag + (long)row * astride + k0 + gcol;
            const unsigned short* gb = Bg + (long)row * bstride + k0 + gcol;
            __builtin_amdgcn_global_load_lds((const __attribute__((address_space(1))) void*)ga,
                                             (__attribute__((address_space(3))) void*)(As + c * 512), 16, 0, 0);
            __builtin_amdgcn_global_load_lds((const __attribute__((address_space(1))) void*)gb,
                                             (__attribute__((address_space(3))) void*)(Bs + c * 512), 16, 0, 0);
        }
        __syncthreads();
#pragma unroll
        for (int kk = 0; kk < 64; kk += 32) {
            short8 a[4], b[4];
#pragma unroll
            for (int t = 0; t < 4; ++t) {
                int arow  = wm + t * 16 + lm;
                int aslot = ((kk >> 3) + q) ^ (arow & 7);
                a[t] = *(const short8*)(As + arow * 64 + aslot * 8);
                int brow  = wn + t * 16 + lm;
                int bslot = ((kk >> 3) + q) ^ (brow & 7);
                b[t] = *(const short8*)(Bs + brow * 64 + bslot * 8);
            }
#pragma unroll
            for (int um = 0; um < 4; ++um)
#pragma unroll
                for (int un = 0; un < 4; ++un)
                    acc[um][un] = __builtin_amdgcn_mfma_f32_16x16x32_bf16(a[um], b[un], acc[um][un], 0, 0, 0);
        }
    }
}

// ---------------------------------------------------------------------------
// gemm_H: Gram partials, split-K over 4 chunks, accumulated with fp32
// atomicAdd into a PACKED upper-triangle buffer G[b][pair][128][128].
// Grid (36, B, 4). No pbuf roundtrip. G must be zeroed beforehand.
// ---------------------------------------------------------------------------
__global__ __launch_bounds__(256, 4) void gemm_H(const unsigned short* __restrict__ magT,
                                                 float* __restrict__ G)
{
    __shared__ unsigned short As[128 * 64];
    __shared__ unsigned short Bs[128 * 64];
    f32x4 acc[4][4];
#pragma unroll
    for (int i = 0; i < 4; ++i)
#pragma unroll
        for (int j = 0; j < 4; ++j) acc[i][j] = (f32x4)0.0f;

    const int pair = blockIdx.x, b = blockIdx.y, kc = blockIdx.z;
    int idx = pair, ty = 0;
    while (idx >= 8 - ty) { idx -= 8 - ty; ++ty; }
    const int tx = ty + idx;                 // tx >= ty

    const unsigned short* Mb = magT + (long)b * D_ * S_ + (long)kc * 512;
    mfma_gemm_128(Mb + (long)ty * 128 * S_, S_,
                  Mb + (long)tx * 128 * S_, S_, 8, As, Bs, acc);

    float* gt = G + ((long)b * NPAIR + pair) * 16384;
    const int tid = threadIdx.x, wave = tid >> 6, lane = tid & 63;
    const int q = lane >> 4, lm = lane & 15;
    const int wm = (wave >> 1) * 64, wn = (wave & 1) * 64;
#pragma unroll
    for (int um = 0; um < 4; ++um)
#pragma unroll
        for (int un = 0; un < 4; ++un) {
            int c = wn + un * 16 + lm;
#pragma unroll
            for (int i = 0; i < 4; ++i) {
                int r = wm + um * 16 + q * 4 + i;
                atomicAdd(gt + r * 128 + c, acc[um][un][i]);
            }
        }
}

// ---------------------------------------------------------------------------
// finalize_H: read raw Gram G_l (packed upper tiles), apply per-layer scale
// damp[r]*damp[c]/(rms^2*S); fused ||H-Hp||^2, ||Hp||^2, diag min/max.
// l==0: Hp = Hprev (full, asymmetric) -> read (r,c) and (c,r).
// l==1: Hp = H0, reconstructed on the fly from raw G0; symmetric -> weight 2.
// ---------------------------------------------------------------------------
__global__ __launch_bounds__(256) void finalize_H(const float* __restrict__ G,
                                                  const float* __restrict__ G0,
                                                  const float* __restrict__ Hprev,
                                                  float* __restrict__ scal,
                                                  const float* __restrict__ dampv, int l)
{
    __shared__ float redd[4], redp[4];
    const int pair = blockIdx.x, b = blockIdx.y;
    int idx0 = pair, ty = 0;
    while (idx0 >= 8 - ty) { idx0 -= 8 - ty; ++ty; }
    const int tx = ty + idx0;
    const int diag_tile = (tx == ty);

    float mean = fmaxf(scal[l] / (float)NTOT, 1e-12f);
    float inv  = 1.0f / fmaxf(sqrtf(mean), 1e-3f);
    const float scale = inv * inv / (float)S_;
    float scale0 = 0.f;
    if (l == 1) {
        float mean0 = fmaxf(scal[0] / (float)NTOT, 1e-12f);
        float inv0  = 1.0f / fmaxf(sqrtf(mean0), 1e-3f);
        scale0 = inv0 * inv0 / (float)S_;
    }
    const float* dl = dampv + (long)l * D_;
    const float* d0 = dampv;

    const float* gt  = G  + ((long)b * NPAIR + pair) * 16384;
    const float* gt0 = (l == 1) ? (G0 + ((long)b * NPAIR + pair) * 16384) : nullptr;

    const int tid = threadIdx.x;
    float d2 = 0.f, p2 = 0.f;
    float dmx = 0.f, dmn = 3.402823466e38f;
    for (int it = 0; it < 64; ++it) {
        int idx = it * 256 + tid;
        int r = idx >> 7, c = idx & 127;
        int gr = ty * 128 + r, gc = tx * 128 + c;
        float h = gt[idx] * scale * dl[gr] * dl[gc];
        if (l == 0) {
            float hp1 = Hprev[(long)b * DD + (long)gr * D_ + gc];
            float df1 = h - hp1;
            if (diag_tile) {
                d2 += df1 * df1; p2 += hp1 * hp1;
            } else {
                float hp2 = Hprev[(long)b * DD + (long)gc * D_ + gr];
                float df2 = h - hp2;
                d2 += df1 * df1 + df2 * df2;
                p2 += hp1 * hp1 + hp2 * hp2;
            }
        } else {
            float hp = gt0[idx] * scale0 * d0[gr] * d0[gc];
            float df = h - hp;
            float w = diag_tile ? 1.0f : 2.0f;
            d2 += w * df * df;
            p2 += w * hp * hp;
        }
        if (diag_tile && gr == gc) { dmx = fmaxf(dmx, h); dmn = fminf(dmn, h); }
    }
    int lane = tid & 63, wave = tid >> 6;
    for (int off = 32; off > 0; off >>= 1) { d2 += __shfl_down(d2, off); p2 += __shfl_down(p2, off); }
    if (lane == 0) { redd[wave] = d2; redp[wave] = p2; }
    if (diag_tile) {
        atomicMax((int*)scal + 18 + l * 4 + b, __float_as_int(dmx));
        atomicMin((int*)scal + 26 + l * 4 + b, __float_as_int(dmn));
    }
    __syncthreads();
    if (tid == 0) {
        atomicAdd(scal + 2 + l * 4 + b,  redd[0] + redd[1] + redd[2] + redd[3]);
        atomicAdd(scal + 10 + l * 4 + b, redp[0] + redp[1] + redp[2] + redp[3]);
    }
}

// A2 <- bf16 pack of x; block 0 inits scalars.
__global__ void init_kernel(const float* __restrict__ xr, const float* __restrict__ xi,
                            unsigned short* __restrict__ A2, float* __restrict__ scal)
{
    if (blockIdx.x == 0 && threadIdx.x < 34)
        scal[threadIdx.x] = (threadIdx.x >= 26) ? 3.402823466e38f : 0.0f;
    long t = (long)blockIdx.x * 256 + threadIdx.x;
    long i = t * 4;
    f32x4 r  = *(const f32x4*)(xr + i);
    f32x4 im = *(const f32x4*)(xi + i);
    long m = i / D_; int d = (int)(i % D_);
    u16x4 rr, ii;
#pragma unroll
    for (int j = 0; j < 4; ++j) { rr[j] = f2bf(r[j]); ii[j] = f2bf(im[j]); }
    *(u16x4*)(A2 + m * K2_ + d) = rr;
    *(u16x4*)(A2 + m * K2_ + D_ + d) = ii;
}

// B2T[n][k] = (B2 - I)[k][n] for layer l
__global__ __launch_bounds__(256) void pack_b2t(const float* __restrict__ Wr_all,
                                                const float* __restrict__ Wi_all,
                                                unsigned short* __restrict__ B2T, int l)
{
    __shared__ float T[64][65];
    const float* Wr = Wr_all + (long)l * DD;
    const float* Wi = Wi_all + (long)l * DD;
    int k0 = blockIdx.x * 64;
    int n0 = blockIdx.y * 64;
    int t = threadIdx.x;
#pragma unroll
    for (int it = 0; it < 16; ++it) {
        int idx = it * 256 + t;
        int kl = idx >> 6, nl = idx & 63;
        int k = k0 + kl, n = n0 + nl;
        float v;
        if (k < D_) v = (n < D_) ? Wr[k * D_ + n] : Wi[k * D_ + (n - D_)];
        else        v = (n < D_) ? -Wi[(k - D_) * D_ + n] : Wr[(k - D_) * D_ + (n - D_)];
        if (k == n) v -= 1.0f;
        T[kl][nl] = v;
    }
    __syncthreads();
#pragma unroll
    for (int it = 0; it < 16; ++it) {
        int idx = it * 256 + t;
        int nl = idx >> 6, kl = idx & 63;
        B2T[(long)(n0 + nl) * K2_ + (k0 + kl)] = f2bf(T[kl][nl]);
    }
}

__global__ void damp_kernel(const float* __restrict__ Lops, float* __restrict__ dampv)
{
    int g = blockIdx.x;
    int l = g >> 2;
    int d = (g & 3) * 256 + threadIdx.x;
    const float* Lp = Lops + (long)l * 4 * D_;
    float s = 0.f;
#pragma unroll
    for (int k = 0; k < 4; ++k) { float v = Lp[k * D_ + d]; s += v * v; }
    dampv[l * D_ + d] = 1.0f - 0.01f * s;
}

// psi_dst = src + bd*damp*factor (complex); factors from scalars; opt A2 repack
__global__ void update_kernel(const unsigned short* __restrict__ bd2,
                              const float* __restrict__ dampv,
                              const float* __restrict__ scal,
                              const float* __restrict__ theta,
                              const float* __restrict__ jscale,
                              const float* __restrict__ kappa, int l,
                              const float* __restrict__ src_r,
                              const float* __restrict__ src_i,
                              float* __restrict__ dst_r,
                              float* __restrict__ dst_i,
                              unsigned short* __restrict__ A2,
                              int write_a2)
{
    long t = (long)blockIdx.x * 256 + threadIdx.x;
    long i = t * 4;
    long m = i / D_; int d = (int)(i % D_);
    int b = (int)(m >> 11);

    float dn = sqrtf(scal[2 + l * 4 + b]);
    float pn = sqrtf(scal[10 + l * 4 + b]);
    float K  = dn / (pn + 1e-6f);
    float mx = __int_as_float(((const int*)scal)[18 + l * 4 + b]);
    float mn = __int_as_float(((const int*)scal)[26 + l * 4 + b]);
    int jumped  = K > kappa[l];
    int escaped = (mx / (mn + 1e-12f)) > 100.0f;
    float js = jumped ? jscale[l] : 1.0f;
    float th = theta[l];
    float fr = js * (escaped ? cosf(th) : 1.0f);
    float fi = js * (escaped ? sinf(th) : 0.0f);

    u16x4 brv = *(const u16x4*)(bd2 + m * N2_ + d);
    u16x4 biv = *(const u16x4*)(bd2 + m * N2_ + D_ + d);
    f32x4 w  = *(const f32x4*)(dampv + d);
    f32x4 pr = *(const f32x4*)(src_r + i);
    f32x4 pi = *(const f32x4*)(src_i + i);
    u16x4 ar, ai;
#pragma unroll
    for (int j = 0; j < 4; ++j) {
        float br = bf2f(brv[j]) * w[j];
        float bi = bf2f(biv[j]) * w[j];
        float nr = pr[j] + br * fr - bi * fi;
        float ni = pi[j] + br * fi + bi * fr;
        pr[j] = nr; pi[j] = ni;
        ar[j] = f2bf(nr); ai[j] = f2bf(ni);
    }
    *(f32x4*)(dst_r + i) = pr;
    *(f32x4*)(dst_i + i) = pi;
    if (write_a2) {
        *(u16x4*)(A2 + m * K2_ + d) = ar;
        *(u16x4*)(A2 + m * K2_ + D_ + d) = ai;
    }
}

extern "C" void kernel_launch(void* const* d_in, const int* in_sizes, int n_in,
                              void* d_out, int out_size, void* d_ws, size_t ws_size,
                              hipStream_t stream)
{
    const float* xr     = (const float*)d_in[0];
    const float* xi     = (const float*)d_in[1];
    const float* Hprev  = (const float*)d_in[2];
    const float* Wr     = (const float*)d_in[3];
    const float* Wi     = (const float*)d_in[4];
    const float* Lops   = (const float*)d_in[5];
    const float* theta  = (const float*)d_in[6];
    const float* jscale = (const float*)d_in[7];
    const float* kappa  = (const float*)d_in[8];

    float* psi_r = (float*)d_out;           // [B,S,D] real plane
    float* psi_i = psi_r + NTOT;            // imag plane

    char* ws = (char*)d_ws;
    unsigned short* A2   = (unsigned short*)ws;               // 32 MiB
    float* G1            = (float*)ws;                        // 9.4 MiB, aliases A2
                                                              // (A2 dead after l=1 gemm_main2)
    unsigned short* B2T  = (unsigned short*)(ws + 33554432);  //  8 MiB (per-layer)
    unsigned short* bd2  = (unsigned short*)(ws + 41943040);  // 32 MiB
    unsigned short* magT = (unsigned short*)(ws + 75497472);  // 16 MiB
    float* G0            = (float*)(ws + 92274688);           // 9.4 MiB (raw Gram, packed tiles)
    float* scal          = (float*)(ws + 109051904);          // scalars + dampv
    float* dampv         = scal + 64;                         // [2][1024]

    init_kernel<<<NTOT / 4 / 256, 256, 0, stream>>>(xr, xi, A2, scal);
    damp_kernel<<<8, 256, 0, stream>>>(Lops, dampv);
    (void)hipMemsetAsync(G0, 0, GBYTES, stream);

    // ---- layer 0 ----
    pack_b2t<<<dim3(32, 32), 256, 0, stream>>>(Wr, Wi, B2T, 0);
    gemm_main2<<<dim3(8, M_ / 128), 256, 0, stream>>>(A2, B2T, bd2, magT, scal, 0);
    gemm_H<<<dim3(NPAIR, B_, 4), 256, 0, stream>>>(magT, G0);
    finalize_H<<<dim3(NPAIR, B_), 256, 0, stream>>>(G0, nullptr, Hprev, scal, dampv, 0);
    update_kernel<<<NTOT / 4 / 256, 256, 0, stream>>>(
        bd2, dampv, scal, theta, jscale, kappa, 0,
        xr, xi, psi_r, psi_i, A2, 1);

    // ---- layer 1 ----
    pack_b2t<<<dim3(32, 32), 256, 0, stream>>>(Wr, Wi, B2T, 1);
    gemm_main2<<<dim3(8, M_ / 128), 256, 0, stream>>>(A2, B2T, bd2, magT, scal, 1);
    (void)hipMemsetAsync(G1, 0, GBYTES, stream);   // A2 dead from here on
    gemm_H<<<dim3(NPAIR, B_, 4), 256, 0, stream>>>(magT, G1);
    finalize_H<<<dim3(NPAIR, B_), 256, 0, stream>>>(G1, G0, nullptr, scal, dampv, 1);
    update_kernel<<<NTOT / 4 / 256, 256, 0, stream>>>(
        bd2, dampv + D_, scal, theta, jscale, kappa, 1,
        psi_r, psi_i, psi_r, psi_i, (unsigned short*)nullptr, 0);
}

// Round 6
// 427.851 us; speedup vs baseline: 1.2807x; 1.2807x over previous
//
#include <hip/hip_runtime.h>

#define B_ 4
#define S_ 2048
#define D_ 1024
#define M_ (B_*S_)           // 8192
#define K2_ 2048
#define N2_ 2048
#define NTOT (B_*S_*D_)      // 8388608
#define DD (D_*D_)           // 1048576

typedef __attribute__((ext_vector_type(4))) float f32x4;
typedef __attribute__((ext_vector_type(8))) short short8;
typedef __attribute__((ext_vector_type(4))) unsigned short u16x4;
typedef __attribute__((ext_vector_type(8))) unsigned short u16x8;

static __device__ __forceinline__ unsigned short f2bf(float f) {
    union { float f; unsigned int u; } v; v.f = f;
    unsigned int u = v.u;
    unsigned int r = (u + 0x7fffu + ((u >> 16) & 1u)) >> 16;
    return (unsigned short)r;
}
static __device__ __forceinline__ float bf2f(unsigned short h) {
    union { unsigned int u; float f; } v; v.u = ((unsigned int)h) << 16;
    return v.f;
}

// scal layout (fp32 slots): [0..1] sumsq[l], [2..9] diff2[l*4+b],
// [10..17] prev2[l*4+b], [18..25] diag-max bits, [26..33] diag-min bits,
// [64..2111] dampv[2][1024]

// ---------------------------------------------------------------------------
// gemm_main2: paired-tile mixing GEMM (905 TF verified r3). Block (nt, mt)
// computes real+imag column tiles against one A tile. Emits bd2, raw |bd|
// transposed into magT[b][d][s], and sum(bd^2).
// ---------------------------------------------------------------------------
__global__ __launch_bounds__(256, 2) void gemm_main2(const unsigned short* __restrict__ A2,
                                                     const unsigned short* __restrict__ B2T,
                                                     unsigned short* __restrict__ bd2,
                                                     unsigned short* __restrict__ magT,
                                                     float* __restrict__ scal, int l)
{
    __shared__ unsigned short smem[3 * 128 * 64];   // 48 KB: As | Bsr | Bsi
    __shared__ float red[4];
    unsigned short* As  = smem;
    unsigned short* Bsr = smem + 8192;
    unsigned short* Bsi = smem + 16384;

    f32x4 accr[4][4], acci[4][4];
#pragma unroll
    for (int i = 0; i < 4; ++i)
#pragma unroll
        for (int j = 0; j < 4; ++j) { accr[i][j] = (f32x4)0.0f; acci[i][j] = (f32x4)0.0f; }

    const int nt = blockIdx.x, mt = blockIdx.y;
    const int tid = threadIdx.x, wave = tid >> 6, lane = tid & 63;
    const int q = lane >> 4, lm = lane & 15;
    const int wm = (wave >> 1) * 64, wn = (wave & 1) * 64;
    const int crow = lane >> 3;
    const int gcol = ((lane & 7) ^ crow) * 8;

    const unsigned short* Ag  = A2  + (long)mt * 128 * K2_;
    const unsigned short* Bgr = B2T + (long)(nt * 128) * K2_;
    const unsigned short* Bgi = B2T + (long)(nt * 128 + 1024) * K2_;

    for (int kt = 0; kt < K2_ / 64; ++kt) {
        const long k0 = (long)kt * 64;
        __syncthreads();
#pragma unroll
        for (int i2 = 0; i2 < 4; ++i2) {
            int c   = i2 * 4 + wave;
            int row = c * 8 + crow;
            long go = (long)row * K2_ + k0 + gcol;
            __builtin_amdgcn_global_load_lds((const __attribute__((address_space(1))) void*)(Ag + go),
                                             (__attribute__((address_space(3))) void*)(As + c * 512), 16, 0, 0);
            __builtin_amdgcn_global_load_lds((const __attribute__((address_space(1))) void*)(Bgr + go),
                                             (__attribute__((address_space(3))) void*)(Bsr + c * 512), 16, 0, 0);
            __builtin_amdgcn_global_load_lds((const __attribute__((address_space(1))) void*)(Bgi + go),
                                             (__attribute__((address_space(3))) void*)(Bsi + c * 512), 16, 0, 0);
        }
        __syncthreads();
#pragma unroll
        for (int kk = 0; kk < 64; kk += 32) {
            short8 a[4], br[4], bi[4];
#pragma unroll
            for (int t = 0; t < 4; ++t) {
                int arow  = wm + t * 16 + lm;
                int aslot = ((kk >> 3) + q) ^ (arow & 7);
                a[t] = *(const short8*)(As + arow * 64 + aslot * 8);
                int brow  = wn + t * 16 + lm;
                int bslot = ((kk >> 3) + q) ^ (brow & 7);
                br[t] = *(const short8*)(Bsr + brow * 64 + bslot * 8);
                bi[t] = *(const short8*)(Bsi + brow * 64 + bslot * 8);
            }
#pragma unroll
            for (int um = 0; um < 4; ++um)
#pragma unroll
                for (int un = 0; un < 4; ++un) {
                    accr[um][un] = __builtin_amdgcn_mfma_f32_16x16x32_bf16(a[um], br[un], accr[um][un], 0, 0, 0);
                    acci[um][un] = __builtin_amdgcn_mfma_f32_16x16x32_bf16(a[um], bi[un], acci[um][un], 0, 0, 0);
                }
        }
    }

    __syncthreads();
    unsigned short* magLds = smem;       // [128 d][136 stride] bf16
    float ss = 0.f;
#pragma unroll
    for (int um = 0; um < 4; ++um) {
#pragma unroll
        for (int un = 0; un < 4; ++un) {
            int colb = wn + un * 16 + lm;
            int coln = nt * 128 + colb;
            u16x4 magv;
#pragma unroll
            for (int i = 0; i < 4; ++i) {
                long rowm = (long)mt * 128 + wm + um * 16 + q * 4 + i;
                float vr = accr[um][un][i];
                float vi = acci[um][un][i];
                bd2[rowm * N2_ + coln]        = f2bf(vr);
                bd2[rowm * N2_ + 1024 + coln] = f2bf(vi);
                float s2 = vr * vr + vi * vi;
                ss += s2;
                magv[i] = f2bf(sqrtf(s2));
            }
            *(u16x4*)(magLds + colb * 136 + wm + um * 16 + q * 4) = magv;
        }
    }
    for (int off = 32; off > 0; off >>= 1) ss += __shfl_down(ss, off);
    if (lane == 0) red[wave] = ss;
    __syncthreads();
    if (tid == 0) atomicAdd(scal + l, red[0] + red[1] + red[2] + red[3]);

    const int b   = mt >> 4;
    const long s0 = (long)(mt & 15) * 128;
#pragma unroll
    for (int it = 0; it < 8; ++it) {
        int sid = it * 256 + tid;
        int row = sid >> 4, seg = sid & 15;
        unsigned short* dst = magT + (long)b * D_ * S_ + (long)(nt * 128 + row) * S_ + s0 + seg * 8;
        *(u16x8*)dst = *(const u16x8*)(magLds + row * 136 + seg * 8);
    }
}

// ---------------------------------------------------------------------------
// gemm_H: fused symmetric Gram, 64x64 tiles, BK=128 (two 64-k panels per
// barrier -> 16 MFMA/barrier), XCD-pinned: grid (8, 68); slot = blockIdx.x;
// linear id = slot + 8*y so (empirical round-robin) slot -> XCD; batch
// b = slot&3, so each XCD streams ONE 4 MB magT stripe == its L2 capacity.
// Epilogue: scale damp[r]*damp[c]/(rms^2*S); fused ||H-Hp||^2, ||Hp||^2,
// diag min/max; mirror H writes (l==0 only; l==1's H is dead data).
// l==1 reads Hp == H in place (each element read by its owning lane).
// ---------------------------------------------------------------------------
__global__ __launch_bounds__(256, 4) void gemm_H(const unsigned short* __restrict__ magT,
                                                 const float* __restrict__ Hp,
                                                 float* __restrict__ H,
                                                 float* __restrict__ scal,
                                                 const float* __restrict__ dampv, int l)
{
    __shared__ unsigned short As[2 * 64 * 64];   // panel p in [p*4096, +4096)
    __shared__ unsigned short Bs[2 * 64 * 64];
    __shared__ float redd[4], redp[4];

    const int slot = blockIdx.x;                 // 0..7 -> XCD (heuristic)
    const int b = slot & 3;
    int pair = (slot >> 2) * 68 + blockIdx.y;    // 0..135
    int idx = pair, ty = 0;
    while (idx >= 16 - ty) { idx -= 16 - ty; ++ty; }
    const int tx = ty + idx;                     // tx >= ty
    const int diag = (tx == ty);

    f32x4 acc[2][2];
#pragma unroll
    for (int i = 0; i < 2; ++i)
#pragma unroll
        for (int j = 0; j < 2; ++j) acc[i][j] = (f32x4)0.0f;

    const int tid = threadIdx.x, wave = tid >> 6, lane = tid & 63;
    const int q = lane >> 4, lm = lane & 15;
    const int wm = (wave >> 1) * 32, wn = (wave & 1) * 32;
    const int crow = lane >> 3;
    const int gcol = ((lane & 7) ^ crow) * 8;

    const unsigned short* Ag = magT + (long)b * D_ * S_ + (long)ty * 64 * S_;
    const unsigned short* Bg = magT + (long)b * D_ * S_ + (long)tx * 64 * S_;

    for (int kt = 0; kt < 16; ++kt) {
        const long k0 = (long)kt * 128;
        __syncthreads();
#pragma unroll
        for (int p = 0; p < 2; ++p) {
#pragma unroll
            for (int i2 = 0; i2 < 2; ++i2) {
                int c   = i2 * 4 + wave;         // chunk 0..7 (8 rows each)
                int row = c * 8 + crow;
                long go = (long)row * S_ + k0 + p * 64 + gcol;
                __builtin_amdgcn_global_load_lds((const __attribute__((address_space(1))) void*)(Ag + go),
                                                 (__attribute__((address_space(3))) void*)(As + p * 4096 + c * 512), 16, 0, 0);
                __builtin_amdgcn_global_load_lds((const __attribute__((address_space(1))) void*)(Bg + go),
                                                 (__attribute__((address_space(3))) void*)(Bs + p * 4096 + c * 512), 16, 0, 0);
            }
        }
        __syncthreads();
#pragma unroll
        for (int p = 0; p < 2; ++p) {
#pragma unroll
            for (int kk = 0; kk < 64; kk += 32) {
                short8 a[2], bb[2];
#pragma unroll
                for (int t = 0; t < 2; ++t) {
                    int arow  = wm + t * 16 + lm;
                    int aslot = ((kk >> 3) + q) ^ (arow & 7);
                    a[t] = *(const short8*)(As + p * 4096 + arow * 64 + aslot * 8);
                    int brow  = wn + t * 16 + lm;
                    int bslot = ((kk >> 3) + q) ^ (brow & 7);
                    bb[t] = *(const short8*)(Bs + p * 4096 + brow * 64 + bslot * 8);
                }
#pragma unroll
                for (int um = 0; um < 2; ++um)
#pragma unroll
                    for (int un = 0; un < 2; ++un)
                        acc[um][un] = __builtin_amdgcn_mfma_f32_16x16x32_bf16(a[um], bb[un], acc[um][un], 0, 0, 0);
            }
        }
    }

    float mean = fmaxf(scal[l] / (float)NTOT, 1e-12f);
    float inv  = 1.0f / fmaxf(sqrtf(mean), 1e-3f);
    const float scale = inv * inv / (float)S_;

    float d2 = 0.f, p2 = 0.f;
    float dmx = 0.f, dmn = 3.402823466e38f;
#pragma unroll
    for (int um = 0; um < 2; ++um) {
#pragma unroll
        for (int un = 0; un < 2; ++un) {
            int coln = tx * 64 + wn + un * 16 + lm;
            float de = dampv[coln];
#pragma unroll
            for (int i = 0; i < 4; ++i) {
                int rowm = ty * 64 + wm + um * 16 + q * 4 + i;
                float h = acc[um][un][i] * scale * dampv[rowm] * de;
                long adr = (long)b * DD + (long)rowm * D_ + coln;
                float hp1 = Hp[adr];
                float df1 = h - hp1;
                if (diag) {
                    if (l == 0) H[adr] = h;
                    d2 += df1 * df1;
                    p2 += hp1 * hp1;
                    if (rowm == coln) { dmx = fmaxf(dmx, h); dmn = fminf(dmn, h); }
                } else {
                    long adrT = (long)b * DD + (long)coln * D_ + rowm;
                    float hp2 = Hp[adrT];
                    if (l == 0) { H[adr] = h; H[adrT] = h; }
                    float df2 = h - hp2;
                    d2 += df1 * df1 + df2 * df2;
                    p2 += hp1 * hp1 + hp2 * hp2;
                }
            }
        }
    }
    for (int off = 32; off > 0; off >>= 1) { d2 += __shfl_down(d2, off); p2 += __shfl_down(p2, off); }
    if (lane == 0) { redd[wave] = d2; redp[wave] = p2; }
    if (diag) {
        for (int off = 32; off > 0; off >>= 1) {
            dmx = fmaxf(dmx, __shfl_down(dmx, off));
            dmn = fminf(dmn, __shfl_down(dmn, off));
        }
        if (lm == 0) {   // lanes whose rows hit the diagonal exist in every wave; reduce covered all
            atomicMax((int*)scal + 18 + l * 4 + b, __float_as_int(dmx));
            atomicMin((int*)scal + 26 + l * 4 + b, __float_as_int(dmn));
        }
    }
    __syncthreads();
    if (tid == 0) {
        atomicAdd(scal + 2 + l * 4 + b,  redd[0] + redd[1] + redd[2] + redd[3]);
        atomicAdd(scal + 10 + l * 4 + b, redp[0] + redp[1] + redp[2] + redp[3]);
    }
}

// A2 <- bf16 pack of x; block 0 inits scalars.
__global__ void init_kernel(const float* __restrict__ xr, const float* __restrict__ xi,
                            unsigned short* __restrict__ A2, float* __restrict__ scal)
{
    if (blockIdx.x == 0 && threadIdx.x < 34)
        scal[threadIdx.x] = (threadIdx.x >= 26) ? 3.402823466e38f : 0.0f;
    long t = (long)blockIdx.x * 256 + threadIdx.x;
    long i = t * 4;
    f32x4 r  = *(const f32x4*)(xr + i);
    f32x4 im = *(const f32x4*)(xi + i);
    long m = i / D_; int d = (int)(i % D_);
    u16x4 rr, ii;
#pragma unroll
    for (int j = 0; j < 4; ++j) { rr[j] = f2bf(r[j]); ii[j] = f2bf(im[j]); }
    *(u16x4*)(A2 + m * K2_ + d) = rr;
    *(u16x4*)(A2 + m * K2_ + D_ + d) = ii;
}

// B2T[n][k] = (B2 - I)[k][n] for layer l
__global__ __launch_bounds__(256) void pack_b2t(const float* __restrict__ Wr_all,
                                                const float* __restrict__ Wi_all,
                                                unsigned short* __restrict__ B2T, int l)
{
    __shared__ float T[64][65];
    const float* Wr = Wr_all + (long)l * DD;
    const float* Wi = Wi_all + (long)l * DD;
    int k0 = blockIdx.x * 64;
    int n0 = blockIdx.y * 64;
    int t = threadIdx.x;
#pragma unroll
    for (int it = 0; it < 16; ++it) {
        int idx = it * 256 + t;
        int kl = idx >> 6, nl = idx & 63;
        int k = k0 + kl, n = n0 + nl;
        float v;
        if (k < D_) v = (n < D_) ? Wr[k * D_ + n] : Wi[k * D_ + (n - D_)];
        else        v = (n < D_) ? -Wi[(k - D_) * D_ + n] : Wr[(k - D_) * D_ + (n - D_)];
        if (k == n) v -= 1.0f;
        T[kl][nl] = v;
    }
    __syncthreads();
#pragma unroll
    for (int it = 0; it < 16; ++it) {
        int idx = it * 256 + t;
        int nl = idx >> 6, kl = idx & 63;
        B2T[(long)(n0 + nl) * K2_ + (k0 + kl)] = f2bf(T[kl][nl]);
    }
}

__global__ void damp_kernel(const float* __restrict__ Lops, float* __restrict__ dampv)
{
    int g = blockIdx.x;
    int l = g >> 2;
    int d = (g & 3) * 256 + threadIdx.x;
    const float* Lp = Lops + (long)l * 4 * D_;
    float s = 0.f;
#pragma unroll
    for (int k = 0; k < 4; ++k) { float v = Lp[k * D_ + d]; s += v * v; }
    dampv[l * D_ + d] = 1.0f - 0.01f * s;
}

// psi_dst = src + bd*damp*factor (complex); factors from scalars; opt A2 repack
__global__ void update_kernel(const unsigned short* __restrict__ bd2,
                              const float* __restrict__ dampv,
                              const float* __restrict__ scal,
                              const float* __restrict__ theta,
                              const float* __restrict__ jscale,
                              const float* __restrict__ kappa, int l,
                              const float* __restrict__ src_r,
                              const float* __restrict__ src_i,
                              float* __restrict__ dst_r,
                              float* __restrict__ dst_i,
                              unsigned short* __restrict__ A2,
                              int write_a2)
{
    long t = (long)blockIdx.x * 256 + threadIdx.x;
    long i = t * 4;
    long m = i / D_; int d = (int)(i % D_);
    int b = (int)(m >> 11);

    float dn = sqrtf(scal[2 + l * 4 + b]);
    float pn = sqrtf(scal[10 + l * 4 + b]);
    float K  = dn / (pn + 1e-6f);
    float mx = __int_as_float(((const int*)scal)[18 + l * 4 + b]);
    float mn = __int_as_float(((const int*)scal)[26 + l * 4 + b]);
    int jumped  = K > kappa[l];
    int escaped = (mx / (mn + 1e-12f)) > 100.0f;
    float js = jumped ? jscale[l] : 1.0f;
    float th = theta[l];
    float fr = js * (escaped ? cosf(th) : 1.0f);
    float fi = js * (escaped ? sinf(th) : 0.0f);

    u16x4 brv = *(const u16x4*)(bd2 + m * N2_ + d);
    u16x4 biv = *(const u16x4*)(bd2 + m * N2_ + D_ + d);
    f32x4 w  = *(const f32x4*)(dampv + d);
    f32x4 pr = *(const f32x4*)(src_r + i);
    f32x4 pi = *(const f32x4*)(src_i + i);
    u16x4 ar, ai;
#pragma unroll
    for (int j = 0; j < 4; ++j) {
        float br = bf2f(brv[j]) * w[j];
        float bi = bf2f(biv[j]) * w[j];
        float nr = pr[j] + br * fr - bi * fi;
        float ni = pi[j] + br * fi + bi * fr;
        pr[j] = nr; pi[j] = ni;
        ar[j] = f2bf(nr); ai[j] = f2bf(ni);
    }
    *(f32x4*)(dst_r + i) = pr;
    *(f32x4*)(dst_i + i) = pi;
    if (write_a2) {
        *(u16x4*)(A2 + m * K2_ + d) = ar;
        *(u16x4*)(A2 + m * K2_ + D_ + d) = ai;
    }
}

extern "C" void kernel_launch(void* const* d_in, const int* in_sizes, int n_in,
                              void* d_out, int out_size, void* d_ws, size_t ws_size,
                              hipStream_t stream)
{
    const float* xr     = (const float*)d_in[0];
    const float* xi     = (const float*)d_in[1];
    const float* Hprev  = (const float*)d_in[2];
    const float* Wr     = (const float*)d_in[3];
    const float* Wi     = (const float*)d_in[4];
    const float* Lops   = (const float*)d_in[5];
    const float* theta  = (const float*)d_in[6];
    const float* jscale = (const float*)d_in[7];
    const float* kappa  = (const float*)d_in[8];

    float* psi_r = (float*)d_out;           // [B,S,D] real plane
    float* psi_i = psi_r + NTOT;            // imag plane

    char* ws = (char*)d_ws;
    unsigned short* A2   = (unsigned short*)ws;               // 32 MiB
    unsigned short* B2T  = (unsigned short*)(ws + 33554432);  //  8 MiB (per-layer)
    unsigned short* bd2  = (unsigned short*)(ws + 41943040);  // 32 MiB
    unsigned short* magT = (unsigned short*)(ws + 75497472);  // 16 MiB
    float* H             = (float*)(ws + 92274688);           // 16 MiB (full, l0 only)
    float* scal          = (float*)(ws + 109051904);          // scalars + dampv
    float* dampv         = scal + 64;                         // [2][1024]

    init_kernel<<<NTOT / 4 / 256, 256, 0, stream>>>(xr, xi, A2, scal);
    damp_kernel<<<8, 256, 0, stream>>>(Lops, dampv);

    // ---- layer 0 ----
    pack_b2t<<<dim3(32, 32), 256, 0, stream>>>(Wr, Wi, B2T, 0);
    gemm_main2<<<dim3(8, M_ / 128), 256, 0, stream>>>(A2, B2T, bd2, magT, scal, 0);
    gemm_H<<<dim3(8, 68), 256, 0, stream>>>(magT, Hprev, H, scal, dampv, 0);
    update_kernel<<<NTOT / 4 / 256, 256, 0, stream>>>(
        bd2, dampv, scal, theta, jscale, kappa, 0,
        xr, xi, psi_r, psi_i, A2, 1);

    // ---- layer 1 ----
    pack_b2t<<<dim3(32, 32), 256, 0, stream>>>(Wr, Wi, B2T, 1);
    gemm_main2<<<dim3(8, M_ / 128), 256, 0, stream>>>(A2, B2T, bd2, magT, scal, 1);
    gemm_H<<<dim3(8, 68), 256, 0, stream>>>(magT, H, H, scal, dampv + D_, 1);
    update_kernel<<<NTOT / 4 / 256, 256, 0, stream>>>(
        bd2, dampv + D_, scal, theta, jscale, kappa, 1,
        psi_r, psi_i, psi_r, psi_i, (unsigned short*)nullptr, 0);
}